// Round 6
// baseline (373.598 us; speedup 1.0000x reference)
//
#include <hip/hip_runtime.h>
#include <hip/hip_bf16.h>

#define EMBED 128
#define HEADS 8
#define DH 16
#define FFN 512
#define BB 16
#define NN 256

typedef float floatx4 __attribute__((ext_vector_type(4)));

// ---------------- Kernel A: LN1 + QKV projection (one block per row) -------
__global__ __launch_bounds__(128) void ln1_qkv_kernel(
    const float* __restrict__ x,
    const float* __restrict__ ln1_g, const float* __restrict__ ln1_b,
    const float* __restrict__ Wq, const float* __restrict__ bq,
    const float* __restrict__ Wk, const float* __restrict__ bk,
    const float* __restrict__ Wv, const float* __restrict__ bv,
    float* __restrict__ q, float* __restrict__ k, float* __restrict__ v)
{
    const int row = blockIdx.x;          // b*N + i
    const int e = threadIdx.x;           // 0..127
    __shared__ float red[128];
    __shared__ float xn[128];

    float xv = x[(size_t)row * EMBED + e];

    red[e] = xv;
    __syncthreads();
    for (int s = 64; s > 0; s >>= 1) { if (e < s) red[e] += red[e + s]; __syncthreads(); }
    float mu = red[0] * (1.0f / EMBED);
    __syncthreads();
    float d = xv - mu;
    red[e] = d * d;
    __syncthreads();
    for (int s = 64; s > 0; s >>= 1) { if (e < s) red[e] += red[e + s]; __syncthreads(); }
    float var = red[0] * (1.0f / EMBED);
    float rs = rsqrtf(var + 1e-5f);
    xn[e] = d * rs * ln1_g[e] + ln1_b[e];
    __syncthreads();

    float aq = bq[e], ak = bk[e], av = bv[e];
    #pragma unroll 8
    for (int c = 0; c < EMBED; ++c) {
        float xc = xn[c];
        aq += xc * Wq[c * EMBED + e];
        ak += xc * Wk[c * EMBED + e];
        av += xc * Wv[c * EMBED + e];
    }
    size_t o = (size_t)row * EMBED + e;
    q[o] = aq; k[o] = ak; v[o] = av;
}

// ---- Kernel B (R5 baseline): scores + softmax -> probs --------------------
__global__ __launch_bounds__(256) void scores_softmax_kernel(
    const float* __restrict__ pe,
    const float* __restrict__ mask,
    const float* __restrict__ q, const float* __restrict__ k,
    float* __restrict__ probs)
{
    const int row = blockIdx.x;      // b*N + i
    const int bb  = row >> 8;        // N = 256
    const int t   = threadIdx.x;     // 0..255

    __shared__ float sc[HEADS][260];
    __shared__ float qs[EMBED];
    __shared__ float msk[NN];

    if (t < EMBED) qs[t] = q[(size_t)row * EMBED + t];
    msk[t] = mask[(size_t)row * NN + t];
    __syncthreads();

    const int g = t >> 5;
    const int l = t & 31;
    float4 q4 = *reinterpret_cast<const float4*>(&qs[4 * l]);

    const size_t pe_row = (size_t)row * NN * EMBED;
    #pragma unroll 4
    for (int jt = 0; jt < 32; ++jt) {
        const int j = jt * 8 + g;
        const float4 p4 = *reinterpret_cast<const float4*>(pe + pe_row + (size_t)j * EMBED + 4 * l);
        const float4 k4 = *reinterpret_cast<const float4*>(k + (size_t)(bb * NN + j) * EMBED + 4 * l);
        float s = q4.x * (k4.x + p4.x) + q4.y * (k4.y + p4.y)
                + q4.z * (k4.z + p4.z) + q4.w * (k4.w + p4.w);
        s += __shfl_xor(s, 1);
        s += __shfl_xor(s, 2);
        if ((l & 3) == 0) {
            sc[l >> 2][j] = s * 0.25f;
        }
    }
    __syncthreads();

    {
        float vals[8];
        float m = -1e30f;
        #pragma unroll
        for (int r = 0; r < 8; ++r) {
            vals[r] = sc[g][l + 32 * r] + msk[l + 32 * r];
            m = fmaxf(m, vals[r]);
        }
        #pragma unroll
        for (int off = 16; off >= 1; off >>= 1) m = fmaxf(m, __shfl_xor(m, off));
        float ssum = 0.f;
        #pragma unroll
        for (int r = 0; r < 8; ++r) { float e2 = __expf(vals[r] - m); vals[r] = e2; ssum += e2; }
        #pragma unroll
        for (int off = 16; off >= 1; off >>= 1) ssum += __shfl_xor(ssum, off);
        float inv = 1.0f / ssum;
        float* pout = probs + ((size_t)row * HEADS + g) * NN;
        #pragma unroll
        for (int r = 0; r < 8; ++r) pout[l + 32 * r] = vals[r] * inv;
    }
}

// ---- Kernel B2 (DIAGNOSTIC variant, output unused): pure-ILP hot loop -----
// Fully unrolled, no cross-lane ops in loop (32 reg partial sums), pe via
// nontemporal loads. Duration shows up as (total - 225.7).
__global__ __launch_bounds__(256) void scores_softmax_v2(
    const float* __restrict__ pe,
    const float* __restrict__ mask,
    const float* __restrict__ q, const float* __restrict__ k,
    float* __restrict__ probs)
{
    const int row = blockIdx.x;
    const int bb  = row >> 8;
    const int t   = threadIdx.x;
    const int g   = t >> 5;
    const int l   = t & 31;

    __shared__ float sc[HEADS][260];
    __shared__ float msk[NN];

    msk[t] = mask[(size_t)row * NN + t];

    const floatx4 q4 = *reinterpret_cast<const floatx4*>(q + (size_t)row * EMBED + 4 * l);
    const size_t pe_row = (size_t)row * NN * EMBED;
    const size_t k_row  = (size_t)bb * NN * EMBED;

    float sacc[32];
    #pragma unroll
    for (int jt = 0; jt < 32; ++jt) {
        const int j = jt * 8 + g;
        const floatx4 p4 = __builtin_nontemporal_load(
            reinterpret_cast<const floatx4*>(pe + pe_row + (size_t)j * EMBED + 4 * l));
        const floatx4 k4 = *reinterpret_cast<const floatx4*>(k + k_row + (size_t)j * EMBED + 4 * l);
        const floatx4 sum = p4 + k4;
        sacc[jt] = q4.x * sum.x + q4.y * sum.y + q4.z * sum.z + q4.w * sum.w;
    }

    #pragma unroll
    for (int jt = 0; jt < 32; ++jt) {
        float s = sacc[jt];
        s += __shfl_xor(s, 1);
        s += __shfl_xor(s, 2);
        if ((l & 3) == 0) sc[l >> 2][jt * 8 + g] = s * 0.25f;
    }
    __syncthreads();

    {
        float vals[8];
        float m = -1e30f;
        #pragma unroll
        for (int r = 0; r < 8; ++r) {
            vals[r] = sc[g][l + 32 * r] + msk[l + 32 * r];
            m = fmaxf(m, vals[r]);
        }
        #pragma unroll
        for (int off = 16; off >= 1; off >>= 1) m = fmaxf(m, __shfl_xor(m, off));
        float ssum = 0.f;
        #pragma unroll
        for (int r = 0; r < 8; ++r) { float e2 = __expf(vals[r] - m); vals[r] = e2; ssum += e2; }
        #pragma unroll
        for (int off = 16; off >= 1; off >>= 1) ssum += __shfl_xor(ssum, off);
        float inv = 1.0f / ssum;
        float* pout = probs + ((size_t)row * HEADS + g) * NN;
        #pragma unroll
        for (int r = 0; r < 8; ++r) pout[l + 32 * r] = vals[r] * inv;
    }
}

// ---- Kernel C: PV + Wo + residual + LN2 + FFN + residual ------------------
__global__ __launch_bounds__(256) void pv_ffn_kernel(
    const float* __restrict__ x,
    const float* __restrict__ probs,
    const float* __restrict__ v,
    const float* __restrict__ Wo, const float* __restrict__ bo,
    const float* __restrict__ ln2_g, const float* __restrict__ ln2_b,
    const float* __restrict__ W1, const float* __restrict__ b1,
    const float* __restrict__ W2, const float* __restrict__ b2,
    float* __restrict__ out)
{
    const int blk  = blockIdx.x;
    const int b    = blk >> 6;
    const int row0 = b * NN + ((blk & 63) << 2);
    const int t    = threadIdx.x;

    __shared__ float ctx[4][EMBED];
    __shared__ float x2s[4][EMBED];
    __shared__ float xn2[4][EMBED];
    __shared__ float hb[4][FFN];
    __shared__ float red4[4][4][EMBED];
    __shared__ float mus[4], rss[4];

    const int e4  = t & 31;
    const int grp = t >> 5;

    {
        const int seg = grp;
        const int h   = e4 >> 2;
        float4 a0 = {0,0,0,0}, a1 = a0, a2 = a0, a3 = a0;
        const float* vb = v + ((size_t)(b * NN + seg * 32)) * EMBED + 4 * e4;
        const size_t p0o = ((size_t)(row0 + 0) * HEADS + h) * NN + seg * 32;
        const size_t p1o = ((size_t)(row0 + 1) * HEADS + h) * NN + seg * 32;
        const size_t p2o = ((size_t)(row0 + 2) * HEADS + h) * NN + seg * 32;
        const size_t p3o = ((size_t)(row0 + 3) * HEADS + h) * NN + seg * 32;
        #pragma unroll 4
        for (int jj = 0; jj < 32; ++jj) {
            const float4 v4 = *reinterpret_cast<const float4*>(vb + (size_t)jj * EMBED);
            const float p0 = probs[p0o + jj];
            const float p1 = probs[p1o + jj];
            const float p2 = probs[p2o + jj];
            const float p3 = probs[p3o + jj];
            a0.x += p0*v4.x; a0.y += p0*v4.y; a0.z += p0*v4.z; a0.w += p0*v4.w;
            a1.x += p1*v4.x; a1.y += p1*v4.y; a1.z += p1*v4.z; a1.w += p1*v4.w;
            a2.x += p2*v4.x; a2.y += p2*v4.y; a2.z += p2*v4.z; a2.w += p2*v4.w;
            a3.x += p3*v4.x; a3.y += p3*v4.y; a3.z += p3*v4.z; a3.w += p3*v4.w;
        }
        a0.x += __shfl_xor(a0.x, 32); a0.y += __shfl_xor(a0.y, 32);
        a0.z += __shfl_xor(a0.z, 32); a0.w += __shfl_xor(a0.w, 32);
        a1.x += __shfl_xor(a1.x, 32); a1.y += __shfl_xor(a1.y, 32);
        a1.z += __shfl_xor(a1.z, 32); a1.w += __shfl_xor(a1.w, 32);
        a2.x += __shfl_xor(a2.x, 32); a2.y += __shfl_xor(a2.y, 32);
        a2.z += __shfl_xor(a2.z, 32); a2.w += __shfl_xor(a2.w, 32);
        a3.x += __shfl_xor(a3.x, 32); a3.y += __shfl_xor(a3.y, 32);
        a3.z += __shfl_xor(a3.z, 32); a3.w += __shfl_xor(a3.w, 32);
        if ((t & 63) < 32) {
            const int w = t >> 6;
            *reinterpret_cast<float4*>(&red4[w][0][4 * e4]) = a0;
            *reinterpret_cast<float4*>(&red4[w][1][4 * e4]) = a1;
            *reinterpret_cast<float4*>(&red4[w][2][4 * e4]) = a2;
            *reinterpret_cast<float4*>(&red4[w][3][4 * e4]) = a3;
        }
    }
    __syncthreads();
    if (t < 128) {
        #pragma unroll
        for (int r = 0; r < 4; ++r)
            ctx[r][t] = red4[0][r][t] + red4[1][r][t] + red4[2][r][t] + red4[3][r][t];
    }
    __syncthreads();

    {
        const int r = grp & 3, ch = grp >> 2;
        float4 wacc = {0,0,0,0};
        const float* Wob = Wo + ch * 64 * EMBED + 4 * e4;
        #pragma unroll 8
        for (int cc = 0; cc < 64; ++cc) {
            const float4 w4 = *reinterpret_cast<const float4*>(Wob + (size_t)cc * EMBED);
            const float xc = ctx[r][ch * 64 + cc];
            wacc.x += xc*w4.x; wacc.y += xc*w4.y; wacc.z += xc*w4.z; wacc.w += xc*w4.w;
        }
        *reinterpret_cast<float4*>(&red4[ch][r][4 * e4]) = wacc;
    }
    __syncthreads();
    {
        #pragma unroll
        for (int rr = 0; rr < 2; ++rr) {
            const int idx = t + 256 * rr;
            const int r = idx >> 7, e = idx & 127;
            x2s[r][e] = red4[0][r][e] + red4[1][r][e] + bo[e]
                      + x[(size_t)(row0 + r) * EMBED + e];
        }
    }
    __syncthreads();

    {
        const int wid = t >> 6, l64 = t & 63;
        const float v0 = x2s[wid][l64], v1 = x2s[wid][l64 + 64];
        float s = v0 + v1;
        float sq = v0 * v0 + v1 * v1;
        #pragma unroll
        for (int off = 32; off >= 1; off >>= 1) {
            s  += __shfl_xor(s, off);
            sq += __shfl_xor(sq, off);
        }
        if (l64 == 0) {
            const float mu = s * (1.0f / EMBED);
            const float var = sq * (1.0f / EMBED) - mu * mu;
            mus[wid] = mu;
            rss[wid] = rsqrtf(var + 1e-5f);
        }
    }
    __syncthreads();
    {
        #pragma unroll
        for (int rr = 0; rr < 2; ++rr) {
            const int idx = t + 256 * rr;
            const int r = idx >> 7, e = idx & 127;
            xn2[r][e] = (x2s[r][e] - mus[r]) * rss[r] * ln2_g[e] + ln2_b[e];
        }
    }
    __syncthreads();

    {
        const int f4 = t & 127, rh = t >> 7;
        const int r0 = 2 * rh, r1 = r0 + 1;
        float4 h0 = *reinterpret_cast<const float4*>(&b1[4 * f4]);
        float4 h1 = h0;
        const float* W1b = W1 + 4 * f4;
        #pragma unroll 8
        for (int c = 0; c < 128; ++c) {
            const float4 w4 = *reinterpret_cast<const float4*>(W1b + (size_t)c * FFN);
            const float xa = xn2[r0][c], xb = xn2[r1][c];
            h0.x += xa*w4.x; h0.y += xa*w4.y; h0.z += xa*w4.z; h0.w += xa*w4.w;
            h1.x += xb*w4.x; h1.y += xb*w4.y; h1.z += xb*w4.z; h1.w += xb*w4.w;
        }
        h0.x = fmaxf(h0.x, 0.f); h0.y = fmaxf(h0.y, 0.f);
        h0.z = fmaxf(h0.z, 0.f); h0.w = fmaxf(h0.w, 0.f);
        h1.x = fmaxf(h1.x, 0.f); h1.y = fmaxf(h1.y, 0.f);
        h1.z = fmaxf(h1.z, 0.f); h1.w = fmaxf(h1.w, 0.f);
        *reinterpret_cast<float4*>(&hb[r0][4 * f4]) = h0;
        *reinterpret_cast<float4*>(&hb[r1][4 * f4]) = h1;
    }
    __syncthreads();

    {
        const int r = grp & 3, fq = grp >> 2;
        float4 facc = {0,0,0,0};
        const float* W2b = W2 + (size_t)fq * 256 * EMBED + 4 * e4;
        #pragma unroll 8
        for (int ff = 0; ff < 256; ++ff) {
            const float4 w4 = *reinterpret_cast<const float4*>(W2b + (size_t)ff * EMBED);
            const float hv = hb[r][fq * 256 + ff];
            facc.x += hv*w4.x; facc.y += hv*w4.y; facc.z += hv*w4.z; facc.w += hv*w4.w;
        }
        *reinterpret_cast<float4*>(&red4[fq][r][4 * e4]) = facc;
    }
    __syncthreads();
    {
        #pragma unroll
        for (int rr = 0; rr < 2; ++rr) {
            const int idx = t + 256 * rr;
            const int r = idx >> 7, e = idx & 127;
            out[(size_t)(row0 + r) * EMBED + e] =
                x2s[r][e] + b2[e] + red4[0][r][e] + red4[1][r][e];
        }
    }
}

extern "C" void kernel_launch(void* const* d_in, const int* in_sizes, int n_in,
                              void* d_out, int out_size, void* d_ws, size_t ws_size,
                              hipStream_t stream) {
    const float* x    = (const float*)d_in[0];
    const float* pe   = (const float*)d_in[1];
    const float* mask = (const float*)d_in[2];
    const float* ln1g = (const float*)d_in[3];
    const float* ln1b = (const float*)d_in[4];
    const float* Wq   = (const float*)d_in[5];
    const float* bq   = (const float*)d_in[6];
    const float* Wk   = (const float*)d_in[7];
    const float* bk   = (const float*)d_in[8];
    const float* Wv   = (const float*)d_in[9];
    const float* bv   = (const float*)d_in[10];
    const float* Wo   = (const float*)d_in[11];
    const float* bo   = (const float*)d_in[12];
    const float* ln2g = (const float*)d_in[13];
    const float* ln2b = (const float*)d_in[14];
    const float* W1   = (const float*)d_in[15];
    const float* b1   = (const float*)d_in[16];
    const float* W2   = (const float*)d_in[17];
    const float* b2   = (const float*)d_in[18];
    float* out = (float*)d_out;

    float* q      = (float*)d_ws;
    float* kk     = q     + (size_t)BB * NN * EMBED;
    float* vv     = kk    + (size_t)BB * NN * EMBED;
    float* probs  = vv    + (size_t)BB * NN * EMBED;              // 33.5 MB
    float* probs2 = probs + (size_t)BB * NN * HEADS * NN;         // 33.5 MB (diagnostic)

    ln1_qkv_kernel<<<BB * NN, 128, 0, stream>>>(x, ln1g, ln1b, Wq, bq, Wk, bk, Wv, bv, q, kk, vv);
    scores_softmax_kernel<<<BB * NN, 256, 0, stream>>>(pe, mask, q, kk, probs);
    scores_softmax_v2<<<BB * NN, 256, 0, stream>>>(pe, mask, q, kk, probs2);   // diagnostic dup
    pv_ffn_kernel<<<BB * NN / 4, 256, 0, stream>>>(x, probs, vv, Wo, bo,
                                                   ln2g, ln2b, W1, b1, W2, b2, out);
}

// Round 7
// 207.685 us; speedup vs baseline: 1.7989x; 1.7989x over previous
//
#include <hip/hip_runtime.h>
#include <hip/hip_bf16.h>

#define EMBED 128
#define HEADS 8
#define DH 16
#define FFN 512
#define BB 16
#define NN 256

typedef float floatx4 __attribute__((ext_vector_type(4)));

// ---------------- Kernel A: LN1 + QKV projection (one block per row) -------
__global__ __launch_bounds__(128) void ln1_qkv_kernel(
    const float* __restrict__ x,
    const float* __restrict__ ln1_g, const float* __restrict__ ln1_b,
    const float* __restrict__ Wq, const float* __restrict__ bq,
    const float* __restrict__ Wk, const float* __restrict__ bk,
    const float* __restrict__ Wv, const float* __restrict__ bv,
    float* __restrict__ q, float* __restrict__ k, float* __restrict__ v)
{
    const int row = blockIdx.x;          // b*N + i
    const int e = threadIdx.x;           // 0..127
    __shared__ float red[128];
    __shared__ float xn[128];

    float xv = x[(size_t)row * EMBED + e];

    red[e] = xv;
    __syncthreads();
    for (int s = 64; s > 0; s >>= 1) { if (e < s) red[e] += red[e + s]; __syncthreads(); }
    float mu = red[0] * (1.0f / EMBED);
    __syncthreads();
    float d = xv - mu;
    red[e] = d * d;
    __syncthreads();
    for (int s = 64; s > 0; s >>= 1) { if (e < s) red[e] += red[e + s]; __syncthreads(); }
    float var = red[0] * (1.0f / EMBED);
    float rs = rsqrtf(var + 1e-5f);
    xn[e] = d * rs * ln1_g[e] + ln1_b[e];
    __syncthreads();

    float aq = bq[e], ak = bk[e], av = bv[e];
    #pragma unroll 8
    for (int c = 0; c < EMBED; ++c) {
        float xc = xn[c];
        aq += xc * Wq[c * EMBED + e];
        ak += xc * Wk[c * EMBED + e];
        av += xc * Wv[c * EMBED + e];
    }
    size_t o = (size_t)row * EMBED + e;
    q[o] = aq; k[o] = ak; v[o] = av;
}

// ---- Kernel B: scores + softmax -> probs ----------------------------------
// Per-block j-order rotated by (row & 31) to decorrelate intra-chunk offsets
// across blocks (anti channel-camping); XCD-chunked block swizzle so each
// XCD reads a contiguous pe region and reuses one batch's k panel in L2.
__global__ __launch_bounds__(256) void scores_softmax_kernel(
    const float* __restrict__ pe,
    const float* __restrict__ mask,
    const float* __restrict__ q, const float* __restrict__ k,
    float* __restrict__ probs)
{
    const int bid = blockIdx.x;
    const int row = (bid & 7) * (BB * NN / 8) + (bid >> 3);  // bijective, 4096%8==0
    const int bb  = row >> 8;        // N = 256
    const int t   = threadIdx.x;     // 0..255

    __shared__ float sc[HEADS][260];
    __shared__ float qs[EMBED];
    __shared__ float msk[NN];

    if (t < EMBED) qs[t] = q[(size_t)row * EMBED + t];
    msk[t] = mask[(size_t)row * NN + t];
    __syncthreads();

    const int g = t >> 5;            // 0..7 (group of 32 lanes)
    const int l = t & 31;            // lane covers dims 4l..4l+3
    float4 q4 = *reinterpret_cast<const float4*>(&qs[4 * l]);

    const size_t pe_row = (size_t)row * NN * EMBED;
    const size_t k_row  = (size_t)bb * NN * EMBED;
    const int rot = row & 31;        // per-block phase rotation

    #pragma unroll 8
    for (int jt0 = 0; jt0 < 32; ++jt0) {
        const int jt = (jt0 + rot) & 31;
        const int j  = jt * 8 + g;
        const floatx4 p4 = __builtin_nontemporal_load(
            reinterpret_cast<const floatx4*>(pe + pe_row + (size_t)j * EMBED + 4 * l));
        const float4 k4 = *reinterpret_cast<const float4*>(k + k_row + (size_t)j * EMBED + 4 * l);
        float s = q4.x * (k4.x + p4.x) + q4.y * (k4.y + p4.y)
                + q4.z * (k4.z + p4.z) + q4.w * (k4.w + p4.w);
        s += __shfl_xor(s, 1);
        s += __shfl_xor(s, 2);
        if ((l & 3) == 0) {
            sc[l >> 2][j] = s * 0.25f;     // 1/sqrt(16)
        }
    }
    __syncthreads();

    // softmax per head; group g handles head g; write probs [row][h][j]
    {
        float vals[8];
        float m = -1e30f;
        #pragma unroll
        for (int r = 0; r < 8; ++r) {
            vals[r] = sc[g][l + 32 * r] + msk[l + 32 * r];
            m = fmaxf(m, vals[r]);
        }
        #pragma unroll
        for (int off = 16; off >= 1; off >>= 1) m = fmaxf(m, __shfl_xor(m, off));
        float ssum = 0.f;
        #pragma unroll
        for (int r = 0; r < 8; ++r) { float e2 = __expf(vals[r] - m); vals[r] = e2; ssum += e2; }
        #pragma unroll
        for (int off = 16; off >= 1; off >>= 1) ssum += __shfl_xor(ssum, off);
        float inv = 1.0f / ssum;
        float* pout = probs + ((size_t)row * HEADS + g) * NN;
        #pragma unroll
        for (int r = 0; r < 8; ++r) pout[l + 32 * r] = vals[r] * inv;
    }
}

// ---- Kernel C: PV + Wo + residual + LN2 + FFN + residual ------------------
__global__ __launch_bounds__(256) void pv_ffn_kernel(
    const float* __restrict__ x,
    const float* __restrict__ probs,
    const float* __restrict__ v,
    const float* __restrict__ Wo, const float* __restrict__ bo,
    const float* __restrict__ ln2_g, const float* __restrict__ ln2_b,
    const float* __restrict__ W1, const float* __restrict__ b1,
    const float* __restrict__ W2, const float* __restrict__ b2,
    float* __restrict__ out)
{
    const int blk  = blockIdx.x;
    const int b    = blk >> 6;
    const int row0 = b * NN + ((blk & 63) << 2);
    const int t    = threadIdx.x;

    __shared__ float ctx[4][EMBED];
    __shared__ float x2s[4][EMBED];
    __shared__ float xn2[4][EMBED];
    __shared__ float hb[4][FFN];
    __shared__ float red4[4][4][EMBED];
    __shared__ float mus[4], rss[4];

    const int e4  = t & 31;
    const int grp = t >> 5;

    {
        const int seg = grp;
        const int h   = e4 >> 2;
        float4 a0 = {0,0,0,0}, a1 = a0, a2 = a0, a3 = a0;
        const float* vb = v + ((size_t)(b * NN + seg * 32)) * EMBED + 4 * e4;
        const size_t p0o = ((size_t)(row0 + 0) * HEADS + h) * NN + seg * 32;
        const size_t p1o = ((size_t)(row0 + 1) * HEADS + h) * NN + seg * 32;
        const size_t p2o = ((size_t)(row0 + 2) * HEADS + h) * NN + seg * 32;
        const size_t p3o = ((size_t)(row0 + 3) * HEADS + h) * NN + seg * 32;
        #pragma unroll 4
        for (int jj = 0; jj < 32; ++jj) {
            const float4 v4 = *reinterpret_cast<const float4*>(vb + (size_t)jj * EMBED);
            const float p0 = probs[p0o + jj];
            const float p1 = probs[p1o + jj];
            const float p2 = probs[p2o + jj];
            const float p3 = probs[p3o + jj];
            a0.x += p0*v4.x; a0.y += p0*v4.y; a0.z += p0*v4.z; a0.w += p0*v4.w;
            a1.x += p1*v4.x; a1.y += p1*v4.y; a1.z += p1*v4.z; a1.w += p1*v4.w;
            a2.x += p2*v4.x; a2.y += p2*v4.y; a2.z += p2*v4.z; a2.w += p2*v4.w;
            a3.x += p3*v4.x; a3.y += p3*v4.y; a3.z += p3*v4.z; a3.w += p3*v4.w;
        }
        a0.x += __shfl_xor(a0.x, 32); a0.y += __shfl_xor(a0.y, 32);
        a0.z += __shfl_xor(a0.z, 32); a0.w += __shfl_xor(a0.w, 32);
        a1.x += __shfl_xor(a1.x, 32); a1.y += __shfl_xor(a1.y, 32);
        a1.z += __shfl_xor(a1.z, 32); a1.w += __shfl_xor(a1.w, 32);
        a2.x += __shfl_xor(a2.x, 32); a2.y += __shfl_xor(a2.y, 32);
        a2.z += __shfl_xor(a2.z, 32); a2.w += __shfl_xor(a2.w, 32);
        a3.x += __shfl_xor(a3.x, 32); a3.y += __shfl_xor(a3.y, 32);
        a3.z += __shfl_xor(a3.z, 32); a3.w += __shfl_xor(a3.w, 32);
        if ((t & 63) < 32) {
            const int w = t >> 6;
            *reinterpret_cast<float4*>(&red4[w][0][4 * e4]) = a0;
            *reinterpret_cast<float4*>(&red4[w][1][4 * e4]) = a1;
            *reinterpret_cast<float4*>(&red4[w][2][4 * e4]) = a2;
            *reinterpret_cast<float4*>(&red4[w][3][4 * e4]) = a3;
        }
    }
    __syncthreads();
    if (t < 128) {
        #pragma unroll
        for (int r = 0; r < 4; ++r)
            ctx[r][t] = red4[0][r][t] + red4[1][r][t] + red4[2][r][t] + red4[3][r][t];
    }
    __syncthreads();

    {
        const int r = grp & 3, ch = grp >> 2;
        float4 wacc = {0,0,0,0};
        const float* Wob = Wo + ch * 64 * EMBED + 4 * e4;
        #pragma unroll 8
        for (int cc = 0; cc < 64; ++cc) {
            const float4 w4 = *reinterpret_cast<const float4*>(Wob + (size_t)cc * EMBED);
            const float xc = ctx[r][ch * 64 + cc];
            wacc.x += xc*w4.x; wacc.y += xc*w4.y; wacc.z += xc*w4.z; wacc.w += xc*w4.w;
        }
        *reinterpret_cast<float4*>(&red4[ch][r][4 * e4]) = wacc;
    }
    __syncthreads();
    {
        #pragma unroll
        for (int rr = 0; rr < 2; ++rr) {
            const int idx = t + 256 * rr;
            const int r = idx >> 7, e = idx & 127;
            x2s[r][e] = red4[0][r][e] + red4[1][r][e] + bo[e]
                      + x[(size_t)(row0 + r) * EMBED + e];
        }
    }
    __syncthreads();

    {
        const int wid = t >> 6, l64 = t & 63;
        const float v0 = x2s[wid][l64], v1 = x2s[wid][l64 + 64];
        float s = v0 + v1;
        float sq = v0 * v0 + v1 * v1;
        #pragma unroll
        for (int off = 32; off >= 1; off >>= 1) {
            s  += __shfl_xor(s, off);
            sq += __shfl_xor(sq, off);
        }
        if (l64 == 0) {
            const float mu = s * (1.0f / EMBED);
            const float var = sq * (1.0f / EMBED) - mu * mu;
            mus[wid] = mu;
            rss[wid] = rsqrtf(var + 1e-5f);
        }
    }
    __syncthreads();
    {
        #pragma unroll
        for (int rr = 0; rr < 2; ++rr) {
            const int idx = t + 256 * rr;
            const int r = idx >> 7, e = idx & 127;
            xn2[r][e] = (x2s[r][e] - mus[r]) * rss[r] * ln2_g[e] + ln2_b[e];
        }
    }
    __syncthreads();

    {
        const int f4 = t & 127, rh = t >> 7;
        const int r0 = 2 * rh, r1 = r0 + 1;
        float4 h0 = *reinterpret_cast<const float4*>(&b1[4 * f4]);
        float4 h1 = h0;
        const float* W1b = W1 + 4 * f4;
        #pragma unroll 8
        for (int c = 0; c < 128; ++c) {
            const float4 w4 = *reinterpret_cast<const float4*>(W1b + (size_t)c * FFN);
            const float xa = xn2[r0][c], xb = xn2[r1][c];
            h0.x += xa*w4.x; h0.y += xa*w4.y; h0.z += xa*w4.z; h0.w += xa*w4.w;
            h1.x += xb*w4.x; h1.y += xb*w4.y; h1.z += xb*w4.z; h1.w += xb*w4.w;
        }
        h0.x = fmaxf(h0.x, 0.f); h0.y = fmaxf(h0.y, 0.f);
        h0.z = fmaxf(h0.z, 0.f); h0.w = fmaxf(h0.w, 0.f);
        h1.x = fmaxf(h1.x, 0.f); h1.y = fmaxf(h1.y, 0.f);
        h1.z = fmaxf(h1.z, 0.f); h1.w = fmaxf(h1.w, 0.f);
        *reinterpret_cast<float4*>(&hb[r0][4 * f4]) = h0;
        *reinterpret_cast<float4*>(&hb[r1][4 * f4]) = h1;
    }
    __syncthreads();

    {
        const int r = grp & 3, fq = grp >> 2;
        float4 facc = {0,0,0,0};
        const float* W2b = W2 + (size_t)fq * 256 * EMBED + 4 * e4;
        #pragma unroll 8
        for (int ff = 0; ff < 256; ++ff) {
            const float4 w4 = *reinterpret_cast<const float4*>(W2b + (size_t)ff * EMBED);
            const float hv = hb[r][fq * 256 + ff];
            facc.x += hv*w4.x; facc.y += hv*w4.y; facc.z += hv*w4.z; facc.w += hv*w4.w;
        }
        *reinterpret_cast<float4*>(&red4[fq][r][4 * e4]) = facc;
    }
    __syncthreads();
    {
        #pragma unroll
        for (int rr = 0; rr < 2; ++rr) {
            const int idx = t + 256 * rr;
            const int r = idx >> 7, e = idx & 127;
            out[(size_t)(row0 + r) * EMBED + e] =
                x2s[r][e] + b2[e] + red4[0][r][e] + red4[1][r][e];
        }
    }
}

extern "C" void kernel_launch(void* const* d_in, const int* in_sizes, int n_in,
                              void* d_out, int out_size, void* d_ws, size_t ws_size,
                              hipStream_t stream) {
    const float* x    = (const float*)d_in[0];
    const float* pe   = (const float*)d_in[1];
    const float* mask = (const float*)d_in[2];
    const float* ln1g = (const float*)d_in[3];
    const float* ln1b = (const float*)d_in[4];
    const float* Wq   = (const float*)d_in[5];
    const float* bq   = (const float*)d_in[6];
    const float* Wk   = (const float*)d_in[7];
    const float* bk   = (const float*)d_in[8];
    const float* Wv   = (const float*)d_in[9];
    const float* bv   = (const float*)d_in[10];
    const float* Wo   = (const float*)d_in[11];
    const float* bo   = (const float*)d_in[12];
    const float* ln2g = (const float*)d_in[13];
    const float* ln2b = (const float*)d_in[14];
    const float* W1   = (const float*)d_in[15];
    const float* b1   = (const float*)d_in[16];
    const float* W2   = (const float*)d_in[17];
    const float* b2   = (const float*)d_in[18];
    float* out = (float*)d_out;

    float* q     = (float*)d_ws;
    float* kk    = q  + (size_t)BB * NN * EMBED;
    float* vv    = kk + (size_t)BB * NN * EMBED;
    float* probs = vv + (size_t)BB * NN * EMBED;   // 33.5 MB

    ln1_qkv_kernel<<<BB * NN, 128, 0, stream>>>(x, ln1g, ln1b, Wq, bq, Wk, bk, Wv, bv, q, kk, vv);
    scores_softmax_kernel<<<BB * NN, 256, 0, stream>>>(pe, mask, q, kk, probs);
    pv_ffn_kernel<<<BB * NN / 4, 256, 0, stream>>>(x, probs, vv, Wo, bo,
                                                   ln2g, ln2b, W1, b1, W2, b2, out);
}